// Round 1
// baseline (442.408 us; speedup 1.0000x reference)
//
#include <hip/hip_runtime.h>

// Problem constants (from reference): img (N,C,H,W) fp32, disp (N,1,H,W) fp32.
#define N_ 4
#define C_ 32
#define H_ 384
#define W_ 1280

// Semantics (faithful to _warp_bilinear_zeros):
//   x  = clip(w - disp, -1, W) + 1            -> x in [0, W+1]
//   x0 = floor(x), x1 = ceil(x), dx = x - x0
//   v(i) = img[n,c,h,i-1] if 1 <= i <= W else 0   (zero pad columns)
//   out  = (1-dx)*v(x0) + dx*v(x1)
//
// One thread per (n,h, w-quad). disp load + coordinate math done once,
// reused across all C=32 channels. float4 loads/stores on disp/out.
__global__ __launch_bounds__(256) void warp1d_kernel(
    const float* __restrict__ img,
    const float* __restrict__ disp,
    float* __restrict__ out)
{
    constexpr int W4 = W_ / 4;
    const int gid = blockIdx.x * blockDim.x + threadIdx.x;
    constexpr int total = N_ * H_ * W4;
    if (gid >= total) return;

    const int w4 = gid % W4;
    const int nh = gid / W4;          // n*H + h
    const int w0 = w4 * 4;

    const float4 d4 = *(const float4*)(disp + (long)nh * W_ + w0);
    const float dv[4] = {d4.x, d4.y, d4.z, d4.w};

    int   i0[4], i1[4];
    float fx[4];
    bool  m0[4], m1[4];
#pragma unroll
    for (int j = 0; j < 4; ++j) {
        float x = (float)(w0 + j) - dv[j];
        x = fminf(fmaxf(x, -1.0f), (float)W_) + 1.0f;
        const float xf = floorf(x);
        const float xc = ceilf(x);
        fx[j] = x - xf;
        const int a = (int)xf - 1;      // index into unpadded row
        const int b = (int)xc - 1;
        m0[j] = (unsigned)a < (unsigned)W_;
        m1[j] = (unsigned)b < (unsigned)W_;
        i0[j] = m0[j] ? a : 0;
        i1[j] = m1[j] ? b : 0;
    }

    const int  n = nh / H_;
    const int  h = nh % H_;
    const long rowbase = ((long)n * C_ * H_ + h) * W_;   // c = 0 row offset

#pragma unroll 4
    for (int c = 0; c < C_; ++c) {
        const float* __restrict__ r = img + rowbase + (long)c * (H_ * W_);
        float4 o;
        float* op = (float*)&o;
#pragma unroll
        for (int j = 0; j < 4; ++j) {
            const float v0 = m0[j] ? r[i0[j]] : 0.0f;
            const float v1 = m1[j] ? r[i1[j]] : 0.0f;
            op[j] = (1.0f - fx[j]) * v0 + fx[j] * v1;
        }
        *(float4*)(out + rowbase + (long)c * (H_ * W_) + w0) = o;
    }
}

extern "C" void kernel_launch(void* const* d_in, const int* in_sizes, int n_in,
                              void* d_out, int out_size, void* d_ws, size_t ws_size,
                              hipStream_t stream) {
    const float* img  = (const float*)d_in[0];
    const float* disp = (const float*)d_in[1];
    float* out = (float*)d_out;

    constexpr int total   = N_ * H_ * (W_ / 4);   // 491,520 threads
    constexpr int block   = 256;
    constexpr int grid    = (total + block - 1) / block;  // 1920 blocks

    warp1d_kernel<<<grid, block, 0, stream>>>(img, disp, out);
}

// Round 2
// 426.898 us; speedup vs baseline: 1.0363x; 1.0363x over previous
//
#include <hip/hip_runtime.h>

// Problem constants (from reference): img (N,C,H,W) fp32, disp (N,1,H,W) fp32.
#define N_ 4
#define C_ 32
#define H_ 384
#define W_ 1280

// One block per (n,h) row. 320 threads = 5 waves; each thread owns a 4-pixel
// quad (320*4 = 1280 = W). Per channel:
//   1. async global->LDS stage of the next channel's row (coalesced,
//      global_load_lds dwordx4: wave w stages bytes [w*1024, w*1024+1024))
//   2. gather current channel from LDS (bilinear taps), blend, float4 store
//   3. __syncthreads() — drains vmcnt (next row staged) + guards LDS reuse
// Double-buffered LDS: 2 x 1280 floats = 10.25 KB.
__device__ __forceinline__ void stage16(const float* g, float* l) {
    __builtin_amdgcn_global_load_lds(
        (const __attribute__((address_space(1))) void*)g,
        (__attribute__((address_space(3))) void*)l, 16, 0, 0);
}

__global__ __launch_bounds__(320) void warp1d_kernel(
    const float* __restrict__ img,
    const float* __restrict__ disp,
    float* __restrict__ out)
{
    __shared__ float buf[2][W_];

    const int tid  = threadIdx.x;
    const int nh   = blockIdx.x;          // n*H + h
    const int w0   = tid * 4;
    const int lane = tid & 63;
    const int wave = tid >> 6;
    // this wave's staging slice within the row (floats)
    const int chunk = wave * 256 + lane * 4;   // 64 lanes * 16B = 1 KiB / wave

    // ---- per-row warp coordinates (computed once, reused for all C) ----
    const float4 d4 = *(const float4*)(disp + (long)nh * W_ + w0);
    const float dv[4] = {d4.x, d4.y, d4.z, d4.w};

    int   i0[4], i1[4];
    float fx[4];
    bool  m0[4], m1[4];
#pragma unroll
    for (int j = 0; j < 4; ++j) {
        float x = (float)(w0 + j) - dv[j];
        x = fminf(fmaxf(x, -1.0f), (float)W_) + 1.0f;   // x in [0, W+1]
        const float xf = floorf(x);
        const float xc = ceilf(x);
        fx[j] = x - xf;
        const int a = (int)xf - 1;        // tap indices into the unpadded row
        const int b = (int)xc - 1;
        m0[j] = (unsigned)a < (unsigned)W_;
        m1[j] = (unsigned)b < (unsigned)W_;
        i0[j] = m0[j] ? a : 0;
        i1[j] = m1[j] ? b : 0;
    }

    const int  n = nh / H_;
    const int  h = nh % H_;
    const long rowbase = ((long)n * C_ * H_ + h) * W_;   // c=0 row offset
    const float* gsrc = img + rowbase + chunk;           // staging src, c=0
    float*       gdst = out + rowbase + w0;              // output dst,  c=0

    // prefetch channel 0 into buf[0]
    stage16(gsrc, &buf[0][wave * 256]);
    gsrc += (long)H_ * W_;
    __syncthreads();   // drains vmcnt -> buf[0] ready

#pragma unroll 2
    for (int c = 0; c < C_; ++c) {
        if (c + 1 < C_) {
            stage16(gsrc, &buf[(c + 1) & 1][wave * 256]);
            gsrc += (long)H_ * W_;
        }
        const float* __restrict__ r = buf[c & 1];
        float4 o;
        float* op = (float*)&o;
#pragma unroll
        for (int j = 0; j < 4; ++j) {
            const float v0 = m0[j] ? r[i0[j]] : 0.0f;
            const float v1 = m1[j] ? r[i1[j]] : 0.0f;
            op[j] = (1.0f - fx[j]) * v0 + fx[j] * v1;
        }
        *(float4*)gdst = o;
        gdst += (long)H_ * W_;
        // one barrier: (a) everyone done reading buf[c&1] before it is
        // re-staged at iter c+1, (b) drains vmcnt so buf[(c+1)&1] is ready.
        __syncthreads();
    }
}

extern "C" void kernel_launch(void* const* d_in, const int* in_sizes, int n_in,
                              void* d_out, int out_size, void* d_ws, size_t ws_size,
                              hipStream_t stream) {
    const float* img  = (const float*)d_in[0];
    const float* disp = (const float*)d_in[1];
    float* out = (float*)d_out;

    constexpr int grid  = N_ * H_;   // 1536 blocks, one per image row
    constexpr int block = 320;       // 5 waves; 4 pixels/thread

    warp1d_kernel<<<grid, block, 0, stream>>>(img, disp, out);
}